// Round 5
// baseline (592.883 us; speedup 1.0000x reference)
//
#include <hip/hip_runtime.h>

// Span masking — bit-exact JAX threefry2x32 stream reproduction.
// One block (1 wave) per row; serial key-chain; LDS bitmask + incremental popcount.
//
// Stream model (modern JAX, jax_threefry_partitionable=True default):
//   split(key,n) foldlike: keys[i] = (y0,y1) of tf(key,(0,i))
//   random_bits(key,32,(128,))[r] = y0^y1 of tf(key,(0,r))
//   _randint: (k1,k2)=split(key,2); higher=bits(k1), lower=bits(k2);
//             span=8192=2^13 -> multiplier=0 -> start = lower[r] & 8191.
//             <-- THE INNER SPLIT was missing in rounds 0-4 (all invalidated).
//   _uniform: bits(key) directly (no inner split).
//
// Template switches for the fallback queue:
//   LEGACY=1: pre-partitionable streams (iota splits, concat(y0,y1) bits).
//   LOWK1=1 : take lower_bits from k1 instead of k2 (randint order flip).
#ifndef LEGACY
#define LEGACY 0
#endif
#ifndef LOWK1
#define LOWK1 0
#endif

static constexpr int kB = 128;
static constexpr int kS = 8192;
static constexpr int kWords = kS / 32;
static constexpr int kMaskTok = 50256;

__device__ __forceinline__ void tf2x32(unsigned k0, unsigned k1,
                                       unsigned x0, unsigned x1,
                                       unsigned& y0, unsigned& y1) {
  const unsigned ks0 = k0, ks1 = k1, ks2 = k0 ^ k1 ^ 0x1BD11BDAu;
  unsigned v0 = x0 + ks0;
  unsigned v1 = x1 + ks1;
#define TF_R(r) do { v0 += v1; v1 = (v1 << (r)) | (v1 >> (32 - (r))); v1 ^= v0; } while (0)
  TF_R(13); TF_R(15); TF_R(26); TF_R(6);
  v0 += ks1; v1 += ks2 + 1u;
  TF_R(17); TF_R(29); TF_R(16); TF_R(24);
  v0 += ks2; v1 += ks0 + 2u;
  TF_R(13); TF_R(15); TF_R(26); TF_R(6);
  v0 += ks0; v1 += ks1 + 3u;
  TF_R(17); TF_R(29); TF_R(16); TF_R(24);
  v0 += ks1; v1 += ks2 + 4u;
  TF_R(13); TF_R(15); TF_R(26); TF_R(6);
  v0 += ks2; v1 += ks0 + 5u;
#undef TF_R
  y0 = v0; y1 = v1;
}

template <int LEG, int LK1>
__global__ __launch_bounds__(64)
void span_mask_kernel(const int* __restrict__ x0tok,
                      const float* __restrict__ mask_prob,
                      int* __restrict__ out) {
  const int r = blockIdx.x;
  const int lane = threadIdx.x;

  __shared__ unsigned maskw[kWords];
  for (int i = lane; i < kWords; i += 64) maskw[i] = 0u;
  __syncthreads();

  const int target = (int)floorf(mask_prob[r] * 8192.0f);  // *2^13 exact
  // f32(log1p(-f32(1/3))) = -13605152 * 2^-25:
  const float Cf = -0.40546512603759765625f;

  unsigned key0 = 0u, key1 = 42u;  // jax.random.key(42)
  int cur = 0;

  for (int it = 0; it < (1 << 17); ++it) {
    if (cur >= target) break;

    // ---- stage A: key, ks, kl = split(key, 3) ------------------------------
    unsigned a0, a1;
    if (!LEG) tf2x32(key0, key1, 0u, (unsigned)lane, a0, a1);          // (0,i)
    else      tf2x32(key0, key1, (unsigned)lane, (unsigned)(lane + 3), a0, a1);
    unsigned nk0, nk1, ks0, ks1, kl0, kl1;
    if (!LEG) {
      nk0 = __shfl(a0, 0); nk1 = __shfl(a1, 0);
      ks0 = __shfl(a0, 1); ks1 = __shfl(a1, 1);
      kl0 = __shfl(a0, 2); kl1 = __shfl(a1, 2);
    } else {  // legacy: concat(y0 of (0,3),(1,4),(2,5); y1 of same) -> (3,2)
      nk0 = __shfl(a0, 0); nk1 = __shfl(a0, 1);
      ks0 = __shfl(a0, 2); ks1 = __shfl(a1, 0);
      kl0 = __shfl(a1, 1); kl1 = __shfl(a1, 2);
    }
    key0 = nk0; key1 = nk1;

    // ---- stage A2: k1, k2 = split(ks, 2) inside _randint -------------------
    unsigned c0, c1;
    if (!LEG) tf2x32(ks0, ks1, 0u, (unsigned)lane, c0, c1);            // (0,i)
    else      tf2x32(ks0, ks1, (unsigned)lane, (unsigned)(lane + 2), c0, c1);
    unsigned rkA, rkB;  // the subkey feeding lower_bits
    if (!LEG) {
      unsigned k1a = __shfl(c0, 0), k1b = __shfl(c1, 0);
      unsigned k2a = __shfl(c0, 1), k2b = __shfl(c1, 1);
      rkA = LK1 ? k1a : k2a; rkB = LK1 ? k1b : k2b;
    } else {  // legacy split(ks,2): concat(y0 of (0,2),(1,3); y1 of same)
      unsigned k1a = __shfl(c0, 0), k1b = __shfl(c0, 1);
      unsigned k2a = __shfl(c1, 0), k2b = __shfl(c1, 1);
      rkA = LK1 ? k1a : k2a; rkB = LK1 ? k1b : k2b;
    }

    // ---- stage B: lane0 start bits (rk), lane1 uniform bits (kl) -----------
    unsigned bk0 = (lane == 0) ? rkA : kl0;
    unsigned bk1 = (lane == 0) ? rkB : kl1;
    unsigned bx0, bx1;
    if (!LEG) { bx0 = 0u; bx1 = (unsigned)r; }                         // (0,r)
    else { bx0 = (unsigned)(r & 63); bx1 = (unsigned)((r & 63) + 64); }
    unsigned b0, b1;
    tf2x32(bk0, bk1, bx0, bx1, b0, b1);
    unsigned sel;
    if (!LEG) sel = b0 ^ b1;                 // partitionable 32-bit condense
    else      sel = (r < 64) ? b0 : b1;      // legacy concat(y0, y1)

    unsigned start = __shfl(sel, 0) & 8191u;  // randint pow2: multiplier=0
    unsigned ubits = __shfl(sel, 1);

    // ---- uniform -> geometric length (uniform across lanes) ----------------
    float f = __uint_as_float((ubits >> 9) | 0x3F800000u) - 1.0f;  // exact
    float val = __fadd_rn(__fmul_rn(f, (1.0f - 1e-7f)), 1e-7f);    // no FMA
    float u = fmaxf(1e-7f, val);
    float lf = (float)log((double)u);   // correctly-rounded f32 log
    float q = __fdiv_rn(lf, Cf);        // f32 divide like XLA
    int geo = (int)floorf(q) + 1;       // 1..40
    int len = min(geo, kS - (int)start);
    int end = (int)start + len;

    // ---- OR span into bitmask (<=3 words), incremental popcount ------------
    int w0 = (int)start >> 5;
    int w1 = (end - 1) >> 5;
    int d = 0;
    int w = w0 + lane;
    if (w <= w1) {
      int lo = max((int)start - (w << 5), 0);
      int hi = min(end - (w << 5), 32);
      unsigned bits = (hi >= 32 ? 0xFFFFFFFFu : ((1u << hi) - 1u))
                      & (0xFFFFFFFFu << lo);
      unsigned old = maskw[w];
      maskw[w] = old | bits;
      d = __popc(bits & ~old);
    }
    d += __shfl_xor(d, 1);
    d += __shfl_xor(d, 2);
    cur += __shfl(d, 0);
  }

  __syncthreads();

  const int base = r * kS;
  for (int j = lane; j < kS; j += 64) {
    unsigned bit = (maskw[j >> 5] >> (j & 31)) & 1u;
    int tok = x0tok[base + j];
    out[base + j] = bit ? kMaskTok : tok;
    out[kB * kS + base + j] = (int)bit;
  }
}

extern "C" void kernel_launch(void* const* d_in, const int* in_sizes, int n_in,
                              void* d_out, int out_size, void* d_ws, size_t ws_size,
                              hipStream_t stream) {
  const int* x0 = (const int*)d_in[0];
  const float* mp = (const float*)d_in[1];
  int* out = (int*)d_out;
  hipLaunchKernelGGL((span_mask_kernel<LEGACY, LOWK1>),
                     dim3(kB), dim3(64), 0, stream, x0, mp, out);
}

// Round 6
// 318.486 us; speedup vs baseline: 1.8616x; 1.8616x over previous
//
#include <hip/hip_runtime.h>

// Span masking — bit-exact JAX threefry2x32 stream (verified R5), batched.
//
// Stream (jax_threefry_partitionable=True):
//   split(key,n): keys[i] = (y0,y1) of tf(key,(0,i))
//   random_bits(key,32,(128,))[r] = y0^y1 of tf(key,(0,r))
//   _randint: (k1,k2)=split(key,2); span=2^13 -> start = bits(k2)[r] & 8191
//   _uniform: bits(key) directly
//
// Structure: only key_{t+1}=tf(key_t,(0,0)) is loop-carried. Batch 64
// iterations: serial chain (lane t saves key_{base+t}) -> per-lane parallel
// draws (5 indep threefrys) -> optimistic commutative span-OR via LDS
// atomicOr + popcount recount. Exact serial replay only on the one batch
// where the row crosses its target.

static constexpr int kB = 128;
static constexpr int kS = 8192;
static constexpr int kWords = kS / 32;   // 256
static constexpr int kMaskTok = 50256;
static constexpr int kBatch = 64;
static constexpr int kMaxBatches = 96;   // 6144 spans >> expected ~700

__device__ __forceinline__ void tf2x32(unsigned k0, unsigned k1,
                                       unsigned x0, unsigned x1,
                                       unsigned& y0, unsigned& y1) {
  const unsigned ks0 = k0, ks1 = k1, ks2 = k0 ^ k1 ^ 0x1BD11BDAu;
  unsigned v0 = x0 + ks0;
  unsigned v1 = x1 + ks1;
#define TF_R(r) do { v0 += v1; v1 = (v1 << (r)) | (v1 >> (32 - (r))); v1 ^= v0; } while (0)
  TF_R(13); TF_R(15); TF_R(26); TF_R(6);
  v0 += ks1; v1 += ks2 + 1u;
  TF_R(17); TF_R(29); TF_R(16); TF_R(24);
  v0 += ks2; v1 += ks0 + 2u;
  TF_R(13); TF_R(15); TF_R(26); TF_R(6);
  v0 += ks0; v1 += ks1 + 3u;
  TF_R(17); TF_R(29); TF_R(16); TF_R(24);
  v0 += ks1; v1 += ks2 + 4u;
  TF_R(13); TF_R(15); TF_R(26); TF_R(6);
  v0 += ks2; v1 += ks0 + 5u;
#undef TF_R
  y0 = v0; y1 = v1;
}

__global__ __launch_bounds__(64)
void span_mask_kernel(const int* __restrict__ x0tok,
                      const float* __restrict__ mask_prob,
                      int* __restrict__ out) {
  const int r = blockIdx.x;
  const int lane = threadIdx.x;

  __shared__ __align__(16) unsigned maskw[kWords];
  for (int i = lane; i < kWords; i += 64) maskw[i] = 0u;
  __syncthreads();

  const int target = (int)floorf(mask_prob[r] * 8192.0f);  // *2^13 exact
  const float Cf = -0.40546512603759765625f;  // f32(log1p(-f32(1/3))) exact

  unsigned key0 = 0u, key1 = 42u;  // jax.random.key(42)
  int cur = 0;

  for (int b = 0; b < kMaxBatches; ++b) {
    // ---- phase 1: 64 serial chain links (irreducible hash chain) ----------
    // lane t keeps key_{b*64+t}; chain itself is wave-uniform (SALU-friendly).
    unsigned mk0 = 0u, mk1 = 0u;
#pragma unroll 1
    for (int t = 0; t < kBatch; ++t) {
      if (lane == t) { mk0 = key0; mk1 = key1; }
      unsigned n0, n1;
      tf2x32(key0, key1, 0u, 0u, n0, n1);   // subkey 0 of split(key,3)
      key0 = n0; key1 = n1;
    }

    // ---- phase 2: per-lane independent draws for iteration b*64+lane ------
    unsigned ksA, ksB, klA, klB, k2A, k2B, d0, d1, e0, e1;
    tf2x32(mk0, mk1, 0u, 1u, ksA, ksB);        // ks = subkey 1
    tf2x32(mk0, mk1, 0u, 2u, klA, klB);        // kl = subkey 2
    tf2x32(ksA, ksB, 0u, 1u, k2A, k2B);        // k2 = split(ks,2)[1]
    tf2x32(k2A, k2B, 0u, (unsigned)r, d0, d1); // start bits
    tf2x32(klA, klB, 0u, (unsigned)r, e0, e1); // uniform bits
    const int start = (int)((d0 ^ d1) & 8191u);
    const unsigned ubits = e0 ^ e1;

    float f = __uint_as_float((ubits >> 9) | 0x3F800000u) - 1.0f;  // exact
    float val = __fadd_rn(__fmul_rn(f, (1.0f - 1e-7f)), 1e-7f);    // no FMA
    float u = fmaxf(1e-7f, val);
    float lf = (float)log((double)u);   // correctly-rounded f32 log
    float q = __fdiv_rn(lf, Cf);
    int geo = (int)floorf(q) + 1;       // 1..40
    int len = min(geo, kS - start);
    const int end = start + len;

    // ---- phase 3: optimistic parallel apply (OR is commutative) -----------
    uint4 pre = *(const uint4*)&maskw[4 * lane];  // pre-batch snapshot
    __syncthreads();
    const int w0 = start >> 5, w1 = (end - 1) >> 5;  // <=3 words (len<=40)
#pragma unroll
    for (int k = 0; k < 3; ++k) {
      int w = w0 + k;
      if (w <= w1) {
        int lo = max(start - (w << 5), 0);
        int hi = min(end - (w << 5), 32);
        unsigned bits = (hi >= 32 ? 0xFFFFFFFFu : ((1u << hi) - 1u))
                        & (0xFFFFFFFFu << lo);
        atomicOr(&maskw[w], bits);
      }
    }
    __syncthreads();
    uint4 post = *(const uint4*)&maskw[4 * lane];
    int t4 = __popc(post.x) + __popc(post.y) + __popc(post.z) + __popc(post.w);
#pragma unroll
    for (int off = 1; off < 64; off <<= 1) t4 += __shfl_xor(t4, off);
    const int newcur = t4;

    if (newcur < target) { cur = newcur; continue; }  // whole batch valid

    // ---- crossing batch: restore pre-state, exact serial replay -----------
    __syncthreads();
    *(uint4*)&maskw[4 * lane] = pre;
    __syncthreads();
#pragma unroll 1
    for (int i = 0; i < kBatch; ++i) {
      if (cur >= target) break;
      int st = __shfl(start, i);
      int en = __shfl(end, i);
      int iw0 = st >> 5, iw1 = (en - 1) >> 5;
      int d = 0;
      int w = iw0 + lane;
      if (w <= iw1) {
        int lo = max(st - (w << 5), 0);
        int hi = min(en - (w << 5), 32);
        unsigned bits = (hi >= 32 ? 0xFFFFFFFFu : ((1u << hi) - 1u))
                        & (0xFFFFFFFFu << lo);
        unsigned old = maskw[w];
        maskw[w] = old | bits;
        d = __popc(bits & ~old);
      }
      d += __shfl_xor(d, 1);
      d += __shfl_xor(d, 2);
      cur += __shfl(d, 0);
    }
    break;  // row done
  }

  __syncthreads();

  const int base = r * kS;
  for (int j = lane; j < kS; j += 64) {
    unsigned bit = (maskw[j >> 5] >> (j & 31)) & 1u;
    int tok = x0tok[base + j];
    out[base + j] = bit ? kMaskTok : tok;
    out[kB * kS + base + j] = (int)bit;
  }
}

extern "C" void kernel_launch(void* const* d_in, const int* in_sizes, int n_in,
                              void* d_out, int out_size, void* d_ws, size_t ws_size,
                              hipStream_t stream) {
  const int* x0 = (const int*)d_in[0];
  const float* mp = (const float*)d_in[1];
  int* out = (int*)d_out;
  hipLaunchKernelGGL(span_mask_kernel, dim3(kB), dim3(64), 0, stream,
                     x0, mp, out);
}

// Round 9
// 233.001 us; speedup vs baseline: 2.5446x; 1.3669x over previous
//
#include <hip/hip_runtime.h>

// Span masking — bit-exact JAX threefry2x32 stream (verified R5/R6), batched,
// serial key chain on the SALU (inline asm; dependent s-ops ~1/cyc vs
// ~900 cyc/link measured on single-wave VALU in R6). Chain keys distributed
// to lanes via v_cndmask (lane==t ternary) — v_writelane with SGPR lane select
// violates the constant-bus rule (R8 compile fail).
//
// Stream (jax_threefry_partitionable=True):
//   split(key,n): keys[i] = (y0,y1) of tf(key,(0,i))
//   random_bits(key,32,(128,))[r] = y0^y1 of tf(key,(0,r))
//   _randint: (k1,k2)=split(key,2); span=2^13 -> start = bits(k2)[r] & 8191
//   _uniform: bits(key) directly

static constexpr int kB = 128;
static constexpr int kS = 8192;
static constexpr int kWords = kS / 32;   // 256
static constexpr int kMaskTok = 50256;
static constexpr int kBatch = 64;
static constexpr int kMaxBatches = 96;

// One SALU threefry round: y0+=y1; y1=rotl(y1,r); y1^=y0.  rr = 32-r.
#define TF_SROUND(r, rr) \
  "s_add_u32 %[y0], %[y0], %[y1]\n\t" \
  "s_lshl_b32 %[t0], %[y1], " #r "\n\t" \
  "s_lshr_b32 %[t1], %[y1], " #rr "\n\t" \
  "s_or_b32 %[y1], %[t0], %[t1]\n\t" \
  "s_xor_b32 %[y1], %[y1], %[y0]\n\t"

// (key0,key1) <- tf2x32(key0,key1, x=(0,0)) entirely in SALU.
// All outputs early-clobber; init done inside asm (avoids in/out aliasing).
__device__ __forceinline__ void tf_link_salu(unsigned& key0, unsigned& key1) {
  unsigned y0, y1, t0, t1, k2;
  asm("s_mov_b32 %[y0], %[k0]\n\t"          // v0 = 0 + ks0
      "s_mov_b32 %[y1], %[k1]\n\t"          // v1 = 0 + ks1
      "s_xor_b32 %[k2], %[k0], %[k1]\n\t"
      "s_xor_b32 %[k2], %[k2], 0x1BD11BDA\n\t"
      TF_SROUND(13, 19) TF_SROUND(15, 17) TF_SROUND(26, 6) TF_SROUND(6, 26)
      "s_add_u32 %[y0], %[y0], %[k1]\n\t"
      "s_add_u32 %[y1], %[y1], %[k2]\n\t"
      "s_add_u32 %[y1], %[y1], 1\n\t"
      TF_SROUND(17, 15) TF_SROUND(29, 3) TF_SROUND(16, 16) TF_SROUND(24, 8)
      "s_add_u32 %[y0], %[y0], %[k2]\n\t"
      "s_add_u32 %[y1], %[y1], %[k0]\n\t"
      "s_add_u32 %[y1], %[y1], 2\n\t"
      TF_SROUND(13, 19) TF_SROUND(15, 17) TF_SROUND(26, 6) TF_SROUND(6, 26)
      "s_add_u32 %[y0], %[y0], %[k0]\n\t"
      "s_add_u32 %[y1], %[y1], %[k1]\n\t"
      "s_add_u32 %[y1], %[y1], 3\n\t"
      TF_SROUND(17, 15) TF_SROUND(29, 3) TF_SROUND(16, 16) TF_SROUND(24, 8)
      "s_add_u32 %[y0], %[y0], %[k1]\n\t"
      "s_add_u32 %[y1], %[y1], %[k2]\n\t"
      "s_add_u32 %[y1], %[y1], 4\n\t"
      TF_SROUND(13, 19) TF_SROUND(15, 17) TF_SROUND(26, 6) TF_SROUND(6, 26)
      "s_add_u32 %[y0], %[y0], %[k2]\n\t"
      "s_add_u32 %[y1], %[y1], %[k0]\n\t"
      "s_add_u32 %[y1], %[y1], 5\n\t"
      : [y0] "=&s"(y0), [y1] "=&s"(y1),
        [t0] "=&s"(t0), [t1] "=&s"(t1), [k2] "=&s"(k2)
      : [k0] "s"(key0), [k1] "s"(key1));
  key0 = y0; key1 = y1;
}

// Per-lane (VALU) threefry — phase-2 draws. Verified R5/R6; unchanged.
__device__ __forceinline__ void tf2x32(unsigned k0, unsigned k1,
                                       unsigned x0, unsigned x1,
                                       unsigned& y0, unsigned& y1) {
  const unsigned ks0 = k0, ks1 = k1, ks2 = k0 ^ k1 ^ 0x1BD11BDAu;
  unsigned v0 = x0 + ks0;
  unsigned v1 = x1 + ks1;
#define TF_R(r) do { v0 += v1; v1 = (v1 << (r)) | (v1 >> (32 - (r))); v1 ^= v0; } while (0)
  TF_R(13); TF_R(15); TF_R(26); TF_R(6);
  v0 += ks1; v1 += ks2 + 1u;
  TF_R(17); TF_R(29); TF_R(16); TF_R(24);
  v0 += ks2; v1 += ks0 + 2u;
  TF_R(13); TF_R(15); TF_R(26); TF_R(6);
  v0 += ks0; v1 += ks1 + 3u;
  TF_R(17); TF_R(29); TF_R(16); TF_R(24);
  v0 += ks1; v1 += ks2 + 4u;
  TF_R(13); TF_R(15); TF_R(26); TF_R(6);
  v0 += ks2; v1 += ks0 + 5u;
#undef TF_R
  y0 = v0; y1 = v1;
}

__global__ __launch_bounds__(64)
void span_mask_kernel(const int* __restrict__ x0tok,
                      const float* __restrict__ mask_prob,
                      int* __restrict__ out) {
  const int r = blockIdx.x;
  const int lane = threadIdx.x;

  __shared__ __align__(16) unsigned maskw[kWords];
  for (int i = lane; i < kWords; i += 64) maskw[i] = 0u;
  __syncthreads();

  const int target = (int)floorf(mask_prob[r] * 8192.0f);  // *2^13 exact
  const float Cf = -0.40546512603759765625f;  // f32(log1p(-f32(1/3))) exact

  unsigned key0 = 0u, key1 = 42u;  // jax.random.key(42)
  int cur = 0;

  for (int b = 0; b < kMaxBatches; ++b) {
    // ---- phase 1: 64 serial chain links on the SALU ------------------------
    // lane t captures key_{b*64+t} via cndmask (v_cmp + v_cndmask: 1 SGPR
    // read per instr — constant-bus legal; co-issues with the SALU chain).
    unsigned mk0 = 0u, mk1 = 0u;
#pragma unroll 1
    for (int t = 0; t < kBatch; ++t) {
      const bool sel = (lane == t);
      mk0 = sel ? key0 : mk0;
      mk1 = sel ? key1 : mk1;
      tf_link_salu(key0, key1);  // key <- subkey 0 of split(key,3)
    }

    // ---- phase 2: per-lane independent draws for iteration b*64+lane ------
    unsigned ksA, ksB, klA, klB, k2A, k2B, d0, d1, e0, e1;
    tf2x32(mk0, mk1, 0u, 1u, ksA, ksB);        // ks = subkey 1
    tf2x32(mk0, mk1, 0u, 2u, klA, klB);        // kl = subkey 2
    tf2x32(ksA, ksB, 0u, 1u, k2A, k2B);        // k2 = split(ks,2)[1]
    tf2x32(k2A, k2B, 0u, (unsigned)r, d0, d1); // start bits
    tf2x32(klA, klB, 0u, (unsigned)r, e0, e1); // uniform bits
    const int start = (int)((d0 ^ d1) & 8191u);
    const unsigned ubits = e0 ^ e1;

    float f = __uint_as_float((ubits >> 9) | 0x3F800000u) - 1.0f;  // exact
    float val = __fadd_rn(__fmul_rn(f, (1.0f - 1e-7f)), 1e-7f);    // no FMA
    float u = fmaxf(1e-7f, val);
    float lf = (float)log((double)u);   // correctly-rounded f32 log
    float q = __fdiv_rn(lf, Cf);
    int geo = (int)floorf(q) + 1;       // 1..40
    int len = min(geo, kS - start);
    const int end = start + len;

    // ---- phase 3: optimistic parallel apply; exact count from atomic rtn --
    uint4 pre = *(const uint4*)&maskw[4 * lane];  // pre-batch snapshot
    __syncthreads();
    const int w0 = start >> 5, w1 = (end - 1) >> 5;  // <=3 words (len<=40)
    int d = 0;
#pragma unroll
    for (int k = 0; k < 3; ++k) {
      int w = w0 + k;
      if (w <= w1) {
        int lo = max(start - (w << 5), 0);
        int hi = min(end - (w << 5), 32);
        unsigned bits = (hi >= 32 ? 0xFFFFFFFFu : ((1u << hi) - 1u))
                        & (0xFFFFFFFFu << lo);
        unsigned old = atomicOr(&maskw[w], bits);
        d += __popc(bits & ~old);   // Σ over all ops = |new union bits| exact
      }
    }
#pragma unroll
    for (int off = 1; off < 64; off <<= 1) d += __shfl_xor(d, off);
    const int newcur = cur + d;

    if (newcur < target) { cur = newcur; continue; }  // whole batch valid

    // ---- crossing batch: restore pre-state, exact serial replay -----------
    __syncthreads();
    *(uint4*)&maskw[4 * lane] = pre;
    __syncthreads();
#pragma unroll 1
    for (int i = 0; i < kBatch; ++i) {
      if (cur >= target) break;
      int st = __shfl(start, i);
      int en = __shfl(end, i);
      int iw0 = st >> 5, iw1 = (en - 1) >> 5;
      int dd = 0;
      int w = iw0 + lane;
      if (w <= iw1) {
        int lo = max(st - (w << 5), 0);
        int hi = min(en - (w << 5), 32);
        unsigned bits = (hi >= 32 ? 0xFFFFFFFFu : ((1u << hi) - 1u))
                        & (0xFFFFFFFFu << lo);
        unsigned old = maskw[w];
        maskw[w] = old | bits;
        dd = __popc(bits & ~old);
      }
      dd += __shfl_xor(dd, 1);
      dd += __shfl_xor(dd, 2);
      cur += __shfl(dd, 0);
    }
    break;  // row done
  }

  __syncthreads();

  // ---- epilogue: int4-vectorized writes of x_masked and mask -------------
  const int base4 = r * (kS / 4);
  for (int i = lane; i < kS / 4; i += 64) {
    int4 tok = ((const int4*)x0tok)[base4 + i];
    unsigned nib = maskw[i >> 3] >> ((i & 7) * 4);
    int4 xm, mm;
    mm.x = (int)(nib & 1u);        xm.x = mm.x ? kMaskTok : tok.x;
    mm.y = (int)((nib >> 1) & 1u); xm.y = mm.y ? kMaskTok : tok.y;
    mm.z = (int)((nib >> 2) & 1u); xm.z = mm.z ? kMaskTok : tok.z;
    mm.w = (int)((nib >> 3) & 1u); xm.w = mm.w ? kMaskTok : tok.w;
    ((int4*)out)[base4 + i] = xm;
    ((int4*)out)[kB * (kS / 4) + base4 + i] = mm;
  }
}

extern "C" void kernel_launch(void* const* d_in, const int* in_sizes, int n_in,
                              void* d_out, int out_size, void* d_ws, size_t ws_size,
                              hipStream_t stream) {
  const int* x0 = (const int*)d_in[0];
  const float* mp = (const float*)d_in[1];
  int* out = (int*)d_out;
  hipLaunchKernelGGL(span_mask_kernel, dim3(kB), dim3(64), 0, stream,
                     x0, mp, out);
}